// Round 15
// baseline (77.358 us; speedup 1.0000x reference)
//
#include <hip/hip_runtime.h>
#include <hip/hip_bf16.h>

// Problem constants:
//   X: (B=16, D=512, 60, 60) fp32 -> N = 3600
//   codewords: (K=32, D=512) fp32, scale: (K=32,) fp32
//   out E: (B, K, D) fp32
constexpr int BB = 16;
constexpr int DD = 512;
constexpr int NN = 3600;
constexpr int KK = 32;
constexpr int SB = 29;     // 128-n windows per batch (464 total)
constexpr int WIN = 128;
constexpr int PAIRS = 232; // 2 windows per block

typedef __attribute__((ext_vector_type(8))) short short8;
typedef __attribute__((ext_vector_type(4))) float f32x4;

__device__ inline unsigned bf16pack(float a, float b) {
    unsigned ia = __float_as_uint(a), ib = __float_as_uint(b);
    ia = (ia + 0x7fffu + ((ia >> 16) & 1u)) >> 16;          // RNE to bf16
    ib = (ib + 0x7fffu + ((ib >> 16) & 1u)) & 0xffff0000u;
    return ia | ib;
}

// raw barrier: orders LDS only; leaves global loads IN FLIGHT (no vmcnt drain)
#define BARL()                                                        \
    do {                                                              \
        asm volatile("s_waitcnt lgkmcnt(0)" ::: "memory");            \
        __builtin_amdgcn_s_barrier();                                 \
        __builtin_amdgcn_sched_barrier(0);                            \
    } while (0)

// ---------------------------------------------------------------------------
// K0: Cbf[k][d] = bf16(Cw[k][d]);  sc2[k] = scale[k]*sum_d C[k,d]^2
// ---------------------------------------------------------------------------
__global__ __launch_bounds__(256) void k0_prep(const float* __restrict__ Cw,
                                               const float* __restrict__ scale,
                                               ushort* __restrict__ Cbf,
                                               float* __restrict__ sc2) {
    __shared__ float buf[8][32];
    const int t = threadIdx.x;
    const int k = t & 31;
    const int h = t >> 5;   // 0..7, 64 d's each
    const float4* row = reinterpret_cast<const float4*>(Cw + k * DD + h * 64);
    uint2* crow = reinterpret_cast<uint2*>(Cbf + k * DD + h * 64);
    float s = 0.f;
#pragma unroll
    for (int j = 0; j < 16; ++j) {
        float4 v = row[j];
        crow[j] = make_uint2(bf16pack(v.x, v.y), bf16pack(v.z, v.w));
        s += v.x * v.x + v.y * v.y + v.z * v.z + v.w * v.w;
    }
    buf[h][k] = s;
    __syncthreads();
    if (t < 32) {
        float tot = 0.f;
#pragma unroll
        for (int j = 0; j < 8; ++j) tot += buf[j][t];
        sc2[t] = scale[t] * tot;
    }
}

// ---------------------------------------------------------------------------
// KF: fused GEMM1 + softmax + GEMM2; TWO windows per block, cross-window
// prefetch. Grid: 232 blocks x 512 threads (one CU round). Per window:
// 4 chunks of 128 d with counted-vmcnt staging (R9/R14); during window-1's
// last chunk the first chunk of window-2 is loaded into registers and stays
// in flight across the whole epilogue (raw lgkm-only barriers, no vmcnt(0)
// drains). Out: Ep bf16 partials + asum partials per window.
// ---------------------------------------------------------------------------
__global__ __launch_bounds__(512) void kf_fused(const float* __restrict__ X,
                                                const ushort* __restrict__ Cbf,
                                                const float* __restrict__ scale,
                                                const float* __restrict__ sc2,
                                                ushort* __restrict__ Epb,
                                                float* __restrict__ asum_part) {
    __shared__ ushort tile[DD * WIN];     // 128 KB, XOR-swizzled
    __shared__ ushort As2[KK * WIN];      // 8 KB, same swizzle per k-row
    __shared__ float x2part[16][WIN];     // 8 KB
    __shared__ float x2s[WIN];
    __shared__ float asw[8][KK];

    const int t = threadIdx.x;
    const int w = t >> 6;     // wave 0..7
    const int l = t & 63;
    const int q = l >> 4;     // 0..3
    const int r = l & 15;     // 0..15
    const int ng = t & 31;    // staging n-group (4 n)
    const int dgs = t >> 5;   // staging d-subrow 0..15

    const int wg0 = blockIdx.x * 2;
    const int wg1 = wg0 + 1;
    const int b0 = wg0 / SB, sb0 = wg0 % SB;
    const int b1 = wg1 / SB, sb1 = wg1 % SB;

    auto make_xsrc = [&](int b, int sb) -> const float* {
        int nst = sb * WIN + ng * 4;
        if (nst > NN - 4) nst = NN - 4;
        return X + (size_t)b * DD * NN + nst;
    };
    const float* xs0 = make_xsrc(b0, sb0);
    const float* xs1 = make_xsrc(b1, sb1);

    const ushort* cb0 = Cbf + r * DD + q * 8;
    const ushort* cb1 = cb0 + 16 * DD;
    const int nloc = w * 16 + r;          // phase-A A-frag row (n)
    const float sk0 = scale[r], sk1 = scale[r + 16];
    const float sq0 = sc2[r],  sq1 = sc2[r + 16];

    float4 bufA[8], bufB[8];

    auto window = [&](int b, int sb, const float* xsrc, const float* xsrc_next,
                      bool skip_first, bool pf_next) {
        const int n0 = sb * WIN;
        f32x4 a0 = {0.f, 0.f, 0.f, 0.f};
        f32x4 a1 = {0.f, 0.f, 0.f, 0.f};
        float x2loc[4] = {0.f, 0.f, 0.f, 0.f};

        if (!skip_first) {
#pragma unroll
            for (int i = 0; i < 8; ++i)
                bufA[i] = *reinterpret_cast<const float4*>(
                    xsrc + (size_t)(dgs * 8 + i) * NN);
        }

        // One chunk = 128 d rows staged + 4 MFMA steps. C-frag loads issued
        // first (oldest) so MFMA's vmcnt wait leaves prefetches flying.
#define CHUNK_BODY(CURB, NXTB, C)                                              \
    {                                                                          \
        short8 cf0[4], cf1[4];                                                 \
        _Pragma("unroll")                                                      \
        for (int u = 0; u < 4; ++u) {                                          \
            cf0[u] = *reinterpret_cast<const short8*>(cb0 + ((C)*4 + u) * 32); \
            cf1[u] = *reinterpret_cast<const short8*>(cb1 + ((C)*4 + u) * 32); \
        }                                                                      \
        if ((C) < 3) {                                                         \
            _Pragma("unroll")                                                  \
            for (int i = 0; i < 8; ++i)                                        \
                NXTB[i] = *reinterpret_cast<const float4*>(                    \
                    xsrc + (size_t)(((C) + 1) * 128 + dgs * 8 + i) * NN);      \
        } else if (pf_next) {                                                  \
            _Pragma("unroll")                                                  \
            for (int i = 0; i < 8; ++i)                                        \
                NXTB[i] = *reinterpret_cast<const float4*>(                    \
                    xsrc_next + (size_t)(dgs * 8 + i) * NN);                   \
        }                                                                      \
        _Pragma("unroll")                                                      \
        for (int i = 0; i < 8; ++i) {                                          \
            const float4 v = CURB[i];                                          \
            x2loc[0] = fmaf(v.x, v.x, x2loc[0]);                               \
            x2loc[1] = fmaf(v.y, v.y, x2loc[1]);                               \
            x2loc[2] = fmaf(v.z, v.z, x2loc[2]);                               \
            x2loc[3] = fmaf(v.w, v.w, x2loc[3]);                               \
            const int d = (C) * 128 + dgs * 8 + i;                             \
            *reinterpret_cast<uint2*>(                                         \
                &tile[d * WIN + ((ng * 4) ^ ((d & 7) << 3))]) =                \
                make_uint2(bf16pack(v.x, v.y), bf16pack(v.z, v.w));            \
        }                                                                      \
        asm volatile("s_waitcnt lgkmcnt(0)" ::: "memory");                     \
        __builtin_amdgcn_s_barrier();                                          \
        __builtin_amdgcn_sched_barrier(0);                                     \
        _Pragma("unroll")                                                      \
        for (int u = 0; u < 4; ++u) {                                          \
            const int s = (C) * 4 + u;                                         \
            union { short8 s8; ushort us[8]; } af;                             \
            _Pragma("unroll")                                                  \
            for (int jj = 0; jj < 8; ++jj)                                     \
                af.us[jj] = tile[(s * 32 + q * 8 + jj) * WIN + (nloc ^ (jj << 3))]; \
            a0 = __builtin_amdgcn_mfma_f32_16x16x32_bf16(af.s8, cf0[u], a0, 0, 0, 0); \
            a1 = __builtin_amdgcn_mfma_f32_16x16x32_bf16(af.s8, cf1[u], a1, 0, 0, 0); \
        }                                                                      \
    }

        CHUNK_BODY(bufA, bufB, 0)
        CHUNK_BODY(bufB, bufA, 1)
        CHUNK_BODY(bufA, bufB, 2)
        CHUNK_BODY(bufB, bufA, 3)   // C==3: prefetches next WINDOW into bufA
#undef CHUNK_BODY

        // ---- x2 reduction (fp32 exact); raw barriers keep prefetch alive ----
        *reinterpret_cast<f32x4*>(&x2part[dgs][ng * 4]) =
            (f32x4){x2loc[0], x2loc[1], x2loc[2], x2loc[3]};
        BARL();
        if (t < WIN) {
            float s = 0.f;
#pragma unroll
            for (int dg = 0; dg < 16; ++dg) s += x2part[dg][t];
            x2s[t] = s;
        }
        BARL();

        // ---- softmax (lane (q,r): n = w*16 + 4q + i, k = r / r+16) ----
        float e0v[4], e1v[4];
        float as0 = 0.f, as1 = 0.f;
#pragma unroll
        for (int i = 0; i < 4; ++i) {
            const float x2v = x2s[w * 16 + 4 * q + i];
            float sl0 = fmaf(sk0, x2v, sq0) - 2.f * sk0 * a0[i];
            float sl1 = fmaf(sk1, x2v, sq1) - 2.f * sk1 * a1[i];
            float m = fmaxf(sl0, sl1);
            m = fmaxf(m, __shfl_xor(m, 1));
            m = fmaxf(m, __shfl_xor(m, 2));
            m = fmaxf(m, __shfl_xor(m, 4));
            m = fmaxf(m, __shfl_xor(m, 8));
            float e0 = __expf(sl0 - m), e1 = __expf(sl1 - m);
            float ssum = e0 + e1;
            ssum += __shfl_xor(ssum, 1);
            ssum += __shfl_xor(ssum, 2);
            ssum += __shfl_xor(ssum, 4);
            ssum += __shfl_xor(ssum, 8);
            const float inv = 1.f / ssum;
            e0 *= inv; e1 *= inv;
            if (n0 + w * 16 + 4 * q + i >= NN) { e0 = 0.f; e1 = 0.f; }
            e0v[i] = e0; e1v[i] = e1;
            as0 += e0; as1 += e1;
        }
        *reinterpret_cast<uint2*>(&As2[r * WIN + ((w * 16 + 4 * q) ^ ((r & 7) << 3))]) =
            make_uint2(bf16pack(e0v[0], e0v[1]), bf16pack(e0v[2], e0v[3]));
        *reinterpret_cast<uint2*>(&As2[(r + 16) * WIN + ((w * 16 + 4 * q) ^ ((r & 7) << 3))]) =
            make_uint2(bf16pack(e1v[0], e1v[1]), bf16pack(e1v[2], e1v[3]));

        as0 += __shfl_xor(as0, 16); as0 += __shfl_xor(as0, 32);
        as1 += __shfl_xor(as1, 16); as1 += __shfl_xor(as1, 32);
        if (l < 16) { asw[w][r] = as0; asw[w][r + 16] = as1; }
        BARL();
        if (t < KK) {
            float s = 0.f;
#pragma unroll
            for (int jw = 0; jw < 8; ++jw) s += asw[jw][t];
            asum_part[((size_t)b * SB + sb) * KK + t] = s;
        }

        // ---- phase B: GEMM2 from tile; wave w owns d in [w*64, w*64+64) ----
        short8 bfr0[4], bfr1[4];
#pragma unroll
        for (int step = 0; step < 4; ++step) {
            bfr0[step] = *reinterpret_cast<const short8*>(
                &As2[r * WIN + ((step * 32 + q * 8) ^ ((r & 7) << 3))]);
            bfr1[step] = *reinterpret_cast<const short8*>(
                &As2[(r + 16) * WIN + ((step * 32 + q * 8) ^ ((r & 7) << 3))]);
        }

        f32x4 acc[4][2];
#pragma unroll
        for (int df = 0; df < 4; ++df) {
            acc[df][0] = (f32x4){0.f, 0.f, 0.f, 0.f};
            acc[df][1] = (f32x4){0.f, 0.f, 0.f, 0.f};
        }

#pragma unroll
        for (int df = 0; df < 4; ++df) {
            const int d = w * 64 + df * 16 + r;   // A-frag row; d&7 == r&7
#pragma unroll
            for (int step = 0; step < 4; ++step) {
                const short8 xa = *reinterpret_cast<const short8*>(
                    &tile[d * WIN + ((step * 32 + q * 8) ^ ((d & 7) << 3))]);
                acc[df][0] = __builtin_amdgcn_mfma_f32_16x16x32_bf16(
                    xa, bfr0[step], acc[df][0], 0, 0, 0);
                acc[df][1] = __builtin_amdgcn_mfma_f32_16x16x32_bf16(
                    xa, bfr1[step], acc[df][1], 0, 0, 0);
            }
        }

        // ---- store Ep partial (bf16) ----
        ushort* ep = Epb + (size_t)(b * SB + sb) * KK * DD;
#pragma unroll
        for (int df = 0; df < 4; ++df) {
#pragma unroll
            for (int kf = 0; kf < 2; ++kf) {
                const int k = kf * 16 + r;
                const int d = w * 64 + df * 16 + q * 4;
                const f32x4 v = acc[df][kf];
                *reinterpret_cast<uint2*>(ep + (size_t)k * DD + d) =
                    make_uint2(bf16pack(v[0], v[1]), bf16pack(v[2], v[3]));
            }
        }
    };

    window(b0, sb0, xs0, xs1, /*skip_first=*/false, /*pf_next=*/true);
    BARL();   // window-0 tile reads complete before window-1 staging writes
    window(b1, sb1, xs1, nullptr, /*skip_first=*/true, /*pf_next=*/false);
}

// ---------------------------------------------------------------------------
// K3: E[b,k,d] = sum_sb bf16(Ep[b,sb,k,d]) - Asum[b,k]*C[k,d]
// Grid: B*K = 512 blocks x 128 threads; lane owns 4 d via one uint2 per
// split (1 KB per wave-instruction, fully coalesced).
// ---------------------------------------------------------------------------
__global__ __launch_bounds__(128) void k3_final(const ushort* __restrict__ Epb,
                                                const float* __restrict__ asum_part,
                                                const float* __restrict__ Cw,
                                                float* __restrict__ E) {
    const int t = threadIdx.x;
    const int b = blockIdx.x >> 5, k = blockIdx.x & 31;

    float asum = 0.f;
#pragma unroll
    for (int sb = 0; sb < SB; ++sb)   // uniform -> scalar loads
        asum += asum_part[((size_t)b * SB + sb) * KK + k];

    const int d = t * 4;
    float s0 = 0.f, s1 = 0.f, s2 = 0.f, s3 = 0.f;
    const ushort* base = Epb + ((size_t)b * SB * KK + k) * DD + d;
#pragma unroll 4
    for (int sb = 0; sb < SB; ++sb) {
        const uint2 u = *reinterpret_cast<const uint2*>(base + (size_t)sb * KK * DD);
        s0 += __uint_as_float(u.x << 16);
        s1 += __uint_as_float(u.x & 0xffff0000u);
        s2 += __uint_as_float(u.y << 16);
        s3 += __uint_as_float(u.y & 0xffff0000u);
    }
    const float4 c = *reinterpret_cast<const float4*>(Cw + k * DD + d);
    float4 o;
    o.x = s0 - asum * c.x;
    o.y = s1 - asum * c.y;
    o.z = s2 - asum * c.z;
    o.w = s3 - asum * c.w;
    *reinterpret_cast<float4*>(E + ((size_t)b * KK + k) * DD + d) = o;
}

// ---------------------------------------------------------------------------
extern "C" void kernel_launch(void* const* d_in, const int* in_sizes, int n_in,
                              void* d_out, int out_size, void* d_ws, size_t ws_size,
                              hipStream_t stream) {
    const float* X     = (const float*)d_in[0];
    const float* Cw    = (const float*)d_in[1];
    const float* scale = (const float*)d_in[2];
    float* E = (float*)d_out;

    // ws layout:
    //   Epb       : 16*29*32*512 ushort = 7,602,176 u16 (~15.2 MB)
    //   asum_part : 464*32 float
    //   sc2       : 32 float
    //   Cbf       : 32*512 ushort
    float* ws = (float*)d_ws;
    ushort* Epb = (ushort*)ws;
    float* asum_part = ws + (size_t)BB * SB * KK * DD / 2;
    float* sc2 = asum_part + (size_t)BB * SB * KK;
    ushort* Cbf = (ushort*)(sc2 + KK);

    k0_prep<<<dim3(1), dim3(256), 0, stream>>>(Cw, scale, Cbf, sc2);
    kf_fused<<<dim3(PAIRS), dim3(512), 0, stream>>>(X, Cbf, scale, sc2, Epb, asum_part);
    k3_final<<<dim3(BB * KK), dim3(128), 0, stream>>>(Epb, asum_part, Cw, E);
}

// Round 16
// 50.056 us; speedup vs baseline: 1.5454x; 1.5454x over previous
//
#include <hip/hip_runtime.h>
#include <hip/hip_bf16.h>

// Problem constants:
//   X: (B=16, D=512, 60, 60) fp32 -> N = 3600
//   codewords: (K=32, D=512) fp32, scale: (K=32,) fp32
//   out E: (B, K, D) fp32
constexpr int BB = 16;
constexpr int DD = 512;
constexpr int NN = 3600;
constexpr int KK = 32;
constexpr int SB = 29;     // 128-n windows per batch
constexpr int WIN = 128;

typedef __attribute__((ext_vector_type(8))) short short8;
typedef __attribute__((ext_vector_type(4))) float f32x4;

__device__ inline unsigned bf16pack(float a, float b) {
    unsigned ia = __float_as_uint(a), ib = __float_as_uint(b);
    ia = (ia + 0x7fffu + ((ia >> 16) & 1u)) >> 16;          // RNE to bf16
    ib = (ib + 0x7fffu + ((ib >> 16) & 1u)) & 0xffff0000u;
    return ia | ib;
}

// ---------------------------------------------------------------------------
// K0: Cbf[k][d] = bf16(Cw[k][d]);  sc2[k] = scale[k]*sum_d C[k,d]^2
// Grid: 32 blocks (one per k) x 256 threads.
// ---------------------------------------------------------------------------
__global__ __launch_bounds__(256) void k0_prep(const float* __restrict__ Cw,
                                               const float* __restrict__ scale,
                                               ushort* __restrict__ Cbf,
                                               float* __restrict__ sc2) {
    __shared__ float red[4];
    const int k = blockIdx.x;
    const int t = threadIdx.x;
    const float2 v = *reinterpret_cast<const float2*>(Cw + k * DD + t * 2);
    *reinterpret_cast<unsigned*>(Cbf + k * DD + t * 2) = bf16pack(v.x, v.y);
    float s = v.x * v.x + v.y * v.y;
#pragma unroll
    for (int o = 1; o < 64; o <<= 1) s += __shfl_xor(s, o);
    if ((t & 63) == 0) red[t >> 6] = s;
    __syncthreads();
    if (t == 0) sc2[k] = scale[k] * (red[0] + red[1] + red[2] + red[3]);
}

// ---------------------------------------------------------------------------
// KF: fused GEMM1 + softmax + GEMM2, async-pipelined staging (R9/R14).
// Grid: B*SB = 464 blocks x 512 threads (8 waves), 1 block/CU (145 KB LDS).
// 4 chunks of 128 d: chunk c+1's global loads stay IN FLIGHT across a raw
// s_barrier (lgkmcnt-only). Phase A: swizzled LDS column u16 A-frags.
// Phase B: row-wise b128 from the same tile. Epilogue: D-tile staged back
// into the dead tile LDS, then FULL-LINE coalesced uint4 stores to
// Epb[b][k][sb][d] bf16 (kills the 4.7x write amplification seen in R15).
// ---------------------------------------------------------------------------
__global__ __launch_bounds__(512) void kf_fused(const float* __restrict__ X,
                                                const ushort* __restrict__ Cbf,
                                                const float* __restrict__ scale,
                                                const float* __restrict__ sc2,
                                                ushort* __restrict__ Epb,
                                                float* __restrict__ asum_part) {
    __shared__ ushort tile[DD * WIN];     // 128 KB, XOR-swizzled
    __shared__ ushort As2[KK * WIN];      // 8 KB, same swizzle per k-row
    __shared__ float x2part[16][WIN];     // 8 KB
    __shared__ float x2s[WIN];
    __shared__ float asw[8][KK];

    const int t = threadIdx.x;
    const int w = t >> 6;     // wave 0..7
    const int l = t & 63;
    const int q = l >> 4;     // 0..3
    const int r = l & 15;     // 0..15
    const int ng = t & 31;    // staging n-group (4 n)
    const int dgs = t >> 5;   // staging d-subrow 0..15
    const int b = blockIdx.x / SB;
    const int sb = blockIdx.x % SB;
    const int n0 = sb * WIN;
    const float* Xb = X + (size_t)b * DD * NN;
    const ushort* cb0 = Cbf + r * DD + q * 8;
    const ushort* cb1 = cb0 + 16 * DD;

    int nst = n0 + ng * 4;
    if (nst > NN - 4) nst = NN - 4;
    const float* xsrc = Xb + nst;

    const int nloc = w * 16 + r;          // phase-A A-frag row (n)
    f32x4 a0 = {0.f, 0.f, 0.f, 0.f};
    f32x4 a1 = {0.f, 0.f, 0.f, 0.f};
    float x2loc[4] = {0.f, 0.f, 0.f, 0.f};

    float4 bufA[8], bufB[8];
#pragma unroll
    for (int i = 0; i < 8; ++i)
        bufA[i] = *reinterpret_cast<const float4*>(xsrc + (size_t)(dgs * 8 + i) * NN);

    // One chunk = 128 d rows staged + 4 MFMA steps. C-frag loads are issued
    // BEFORE the next-chunk prefetch so the MFMA's vmcnt wait (oldest-first)
    // leaves the prefetch in flight.
#define CHUNK_BODY(CURB, NXTB, C)                                              \
    {                                                                          \
        short8 cf0[4], cf1[4];                                                 \
        _Pragma("unroll")                                                      \
        for (int u = 0; u < 4; ++u) {                                          \
            cf0[u] = *reinterpret_cast<const short8*>(cb0 + ((C)*4 + u) * 32); \
            cf1[u] = *reinterpret_cast<const short8*>(cb1 + ((C)*4 + u) * 32); \
        }                                                                      \
        if ((C) < 3) {                                                         \
            _Pragma("unroll")                                                  \
            for (int i = 0; i < 8; ++i)                                        \
                NXTB[i] = *reinterpret_cast<const float4*>(                    \
                    xsrc + (size_t)(((C) + 1) * 128 + dgs * 8 + i) * NN);      \
        }                                                                      \
        _Pragma("unroll")                                                      \
        for (int i = 0; i < 8; ++i) {                                          \
            const float4 v = CURB[i];                                          \
            x2loc[0] = fmaf(v.x, v.x, x2loc[0]);                               \
            x2loc[1] = fmaf(v.y, v.y, x2loc[1]);                               \
            x2loc[2] = fmaf(v.z, v.z, x2loc[2]);                               \
            x2loc[3] = fmaf(v.w, v.w, x2loc[3]);                               \
            const int d = (C) * 128 + dgs * 8 + i;                             \
            *reinterpret_cast<uint2*>(                                         \
                &tile[d * WIN + ((ng * 4) ^ ((d & 7) << 3))]) =                \
                make_uint2(bf16pack(v.x, v.y), bf16pack(v.z, v.w));            \
        }                                                                      \
        asm volatile("s_waitcnt lgkmcnt(0)" ::: "memory");                     \
        __builtin_amdgcn_s_barrier();                                          \
        __builtin_amdgcn_sched_barrier(0);                                     \
        _Pragma("unroll")                                                      \
        for (int u = 0; u < 4; ++u) {                                          \
            const int s = (C) * 4 + u;                                         \
            union { short8 s8; ushort us[8]; } af;                             \
            _Pragma("unroll")                                                  \
            for (int jj = 0; jj < 8; ++jj)                                     \
                af.us[jj] = tile[(s * 32 + q * 8 + jj) * WIN + (nloc ^ (jj << 3))]; \
            a0 = __builtin_amdgcn_mfma_f32_16x16x32_bf16(af.s8, cf0[u], a0, 0, 0, 0); \
            a1 = __builtin_amdgcn_mfma_f32_16x16x32_bf16(af.s8, cf1[u], a1, 0, 0, 0); \
        }                                                                      \
    }

    CHUNK_BODY(bufA, bufB, 0)
    CHUNK_BODY(bufB, bufA, 1)
    CHUNK_BODY(bufA, bufB, 2)
    CHUNK_BODY(bufB, bufA, 3)
#undef CHUNK_BODY

    // ---- x2 reduction (fp32 exact) ----
    *reinterpret_cast<f32x4*>(&x2part[dgs][ng * 4]) =
        (f32x4){x2loc[0], x2loc[1], x2loc[2], x2loc[3]};
    __syncthreads();   // no vmem in flight now -> drain harmless
    if (t < WIN) {
        float s = 0.f;
#pragma unroll
        for (int dg = 0; dg < 16; ++dg) s += x2part[dg][t];
        x2s[t] = s;
    }
    __syncthreads();

    // ---- softmax (lane (q,r): n = w*16 + 4q + i, k = r / r+16) ----
    const float sk0 = scale[r], sk1 = scale[r + 16];
    const float sq0 = sc2[r],  sq1 = sc2[r + 16];
    float e0v[4], e1v[4];
    float as0 = 0.f, as1 = 0.f;
#pragma unroll
    for (int i = 0; i < 4; ++i) {
        const float x2v = x2s[w * 16 + 4 * q + i];
        float sl0 = fmaf(sk0, x2v, sq0) - 2.f * sk0 * a0[i];
        float sl1 = fmaf(sk1, x2v, sq1) - 2.f * sk1 * a1[i];
        float m = fmaxf(sl0, sl1);
        m = fmaxf(m, __shfl_xor(m, 1));
        m = fmaxf(m, __shfl_xor(m, 2));
        m = fmaxf(m, __shfl_xor(m, 4));
        m = fmaxf(m, __shfl_xor(m, 8));
        float e0 = __expf(sl0 - m), e1 = __expf(sl1 - m);
        float ssum = e0 + e1;
        ssum += __shfl_xor(ssum, 1);
        ssum += __shfl_xor(ssum, 2);
        ssum += __shfl_xor(ssum, 4);
        ssum += __shfl_xor(ssum, 8);
        const float inv = 1.f / ssum;
        e0 *= inv; e1 *= inv;
        if (n0 + w * 16 + 4 * q + i >= NN) { e0 = 0.f; e1 = 0.f; }
        e0v[i] = e0; e1v[i] = e1;
        as0 += e0; as1 += e1;
    }
    *reinterpret_cast<uint2*>(&As2[r * WIN + ((w * 16 + 4 * q) ^ ((r & 7) << 3))]) =
        make_uint2(bf16pack(e0v[0], e0v[1]), bf16pack(e0v[2], e0v[3]));
    *reinterpret_cast<uint2*>(&As2[(r + 16) * WIN + ((w * 16 + 4 * q) ^ ((r & 7) << 3))]) =
        make_uint2(bf16pack(e1v[0], e1v[1]), bf16pack(e1v[2], e1v[3]));

    as0 += __shfl_xor(as0, 16); as0 += __shfl_xor(as0, 32);
    as1 += __shfl_xor(as1, 16); as1 += __shfl_xor(as1, 32);
    if (l < 16) { asw[w][r] = as0; asw[w][r + 16] = as1; }
    __syncthreads();
    if (t < KK) {
        float s = 0.f;
#pragma unroll
        for (int jw = 0; jw < 8; ++jw) s += asw[jw][t];
        asum_part[((size_t)b * SB + sb) * KK + t] = s;
    }

    // ---- phase B: GEMM2 from the tile; wave w owns d in [w*64, w*64+64) ----
    short8 bfr0[4], bfr1[4];
#pragma unroll
    for (int step = 0; step < 4; ++step) {
        bfr0[step] = *reinterpret_cast<const short8*>(
            &As2[r * WIN + ((step * 32 + q * 8) ^ ((r & 7) << 3))]);
        bfr1[step] = *reinterpret_cast<const short8*>(
            &As2[(r + 16) * WIN + ((step * 32 + q * 8) ^ ((r & 7) << 3))]);
    }

    f32x4 acc[4][2];
#pragma unroll
    for (int df = 0; df < 4; ++df) {
        acc[df][0] = (f32x4){0.f, 0.f, 0.f, 0.f};
        acc[df][1] = (f32x4){0.f, 0.f, 0.f, 0.f};
    }

#pragma unroll
    for (int df = 0; df < 4; ++df) {
        const int d = w * 64 + df * 16 + r;   // A-frag row; d&7 == r&7
#pragma unroll
        for (int step = 0; step < 4; ++step) {
            const short8 xa = *reinterpret_cast<const short8*>(
                &tile[d * WIN + ((step * 32 + q * 8) ^ ((d & 7) << 3))]);
            acc[df][0] = __builtin_amdgcn_mfma_f32_16x16x32_bf16(
                xa, bfr0[step], acc[df][0], 0, 0, 0);
            acc[df][1] = __builtin_amdgcn_mfma_f32_16x16x32_bf16(
                xa, bfr1[step], acc[df][1], 0, 0, 0);
        }
    }

    // ---- epilogue: stage D-tile (32k x 512d bf16) into dead tile LDS,
    //      then full-line coalesced uint4 stores to Epb[b][k][sb][d] ----
    __syncthreads();   // all phase-B tile reads complete
#pragma unroll
    for (int df = 0; df < 4; ++df) {
#pragma unroll
        for (int kf = 0; kf < 2; ++kf) {
            const int k = kf * 16 + r;
            const int d = w * 64 + df * 16 + q * 4;
            const f32x4 v = acc[df][kf];
            *reinterpret_cast<uint2*>(&tile[k * DD + (d ^ ((k & 7) << 3))]) =
                make_uint2(bf16pack(v[0], v[1]), bf16pack(v[2], v[3]));
        }
    }
    __syncthreads();
    {
        ushort* ep = Epb + (((size_t)b * KK) * SB + sb) * DD;
#pragma unroll
        for (int p = 0; p < 4; ++p) {
            const int g = p * 512 + t;    // elem-group of 8
            const int k = g >> 6;         // 0..31
            const int gc = g & 63;
            const uint4 vv = *reinterpret_cast<const uint4*>(
                &tile[k * DD + ((gc * 8) ^ ((k & 7) << 3))]);
            *reinterpret_cast<uint4*>(ep + (size_t)k * SB * DD + gc * 8) = vv;
        }
    }
}

// ---------------------------------------------------------------------------
// K3: E[b,k,d] = sum_sb bf16(Epb[b,k,sb,d]) - Asum[b,k]*C[k,d]
// Grid: B*K = 512 blocks x 128 threads. Per (b,k) the 29x512 bf16 partials
// are CONTIGUOUS (29 KB sequential stream per block).
// ---------------------------------------------------------------------------
__global__ __launch_bounds__(128) void k3_final(const ushort* __restrict__ Epb,
                                                const float* __restrict__ asum_part,
                                                const float* __restrict__ Cw,
                                                float* __restrict__ E) {
    const int t = threadIdx.x;
    const int b = blockIdx.x >> 5, k = blockIdx.x & 31;

    float asum = 0.f;
#pragma unroll
    for (int sb = 0; sb < SB; ++sb)   // uniform -> scalar loads
        asum += asum_part[((size_t)b * SB + sb) * KK + k];

    const int d = t * 4;
    float s0 = 0.f, s1 = 0.f, s2 = 0.f, s3 = 0.f;
    const ushort* base = Epb + ((size_t)(b * KK + k)) * SB * DD + d;
#pragma unroll 4
    for (int sb = 0; sb < SB; ++sb) {
        const uint2 u = *reinterpret_cast<const uint2*>(base + (size_t)sb * DD);
        s0 += __uint_as_float(u.x << 16);
        s1 += __uint_as_float(u.x & 0xffff0000u);
        s2 += __uint_as_float(u.y << 16);
        s3 += __uint_as_float(u.y & 0xffff0000u);
    }
    const float4 c = *reinterpret_cast<const float4*>(Cw + k * DD + d);
    float4 o;
    o.x = s0 - asum * c.x;
    o.y = s1 - asum * c.y;
    o.z = s2 - asum * c.z;
    o.w = s3 - asum * c.w;
    *reinterpret_cast<float4*>(E + ((size_t)b * KK + k) * DD + d) = o;
}

// ---------------------------------------------------------------------------
extern "C" void kernel_launch(void* const* d_in, const int* in_sizes, int n_in,
                              void* d_out, int out_size, void* d_ws, size_t ws_size,
                              hipStream_t stream) {
    const float* X     = (const float*)d_in[0];
    const float* Cw    = (const float*)d_in[1];
    const float* scale = (const float*)d_in[2];
    float* E = (float*)d_out;

    // ws layout:
    //   Epb       : 16*32*29*512 ushort = 7,602,176 u16 (~15.2 MB)
    //   asum_part : 464*32 float
    //   sc2       : 32 float
    //   Cbf       : 32*512 ushort
    float* ws = (float*)d_ws;
    ushort* Epb = (ushort*)ws;
    float* asum_part = ws + (size_t)BB * SB * KK * DD / 2;
    float* sc2 = asum_part + (size_t)BB * SB * KK;
    ushort* Cbf = (ushort*)(sc2 + KK);

    k0_prep<<<dim3(KK), dim3(256), 0, stream>>>(Cw, scale, Cbf, sc2);
    kf_fused<<<dim3(BB * SB), dim3(512), 0, stream>>>(X, Cbf, scale, sc2, Epb, asum_part);
    k3_final<<<dim3(BB * KK), dim3(128), 0, stream>>>(Epb, asum_part, Cw, E);
}